// Round 7
// baseline (64.819 us; speedup 1.0000x reference)
//
#include <hip/hip_runtime.h>
#include <cfloat>

#define HD 1024
#define LS 2048
#define NB 16
#define NCH 128              // chunks per batch
#define LPER (LS / NCH)      // 16 rows per chunk

struct f4 { float x, y, z, w; };
typedef float v4f __attribute__((ext_vector_type(4)));

__device__ inline f4 ld4(const float* p) { return *reinterpret_cast<const f4*>(p); }

__device__ inline f4 ldnt4(const float* p) {
    v4f v = __builtin_nontemporal_load(reinterpret_cast<const v4f*>(p));
    f4 r; r.x = v.x; r.y = v.y; r.z = v.z; r.w = v.w; return r;
}

__device__ inline float ftanh(float x) {
    x = fminf(10.f, fmaxf(-10.f, x));
    float t = __expf(2.f * x);
    return 1.f - 2.f * __builtin_amdgcn_rcpf(t + 1.f);
}

__device__ inline float dotTanh(const f4& s, const f4& q, const f4& wc, const f4& v, float covs) {
    return ftanh(s.x + q.x + covs * wc.x) * v.x
         + ftanh(s.y + q.y + covs * wc.y) * v.y
         + ftanh(s.z + q.z + covs * wc.z) * v.z
         + ftanh(s.w + q.w + covs * wc.w) * v.w;
}

__device__ inline float waveReduce(float v) {
    #pragma unroll
    for (int off = 32; off; off >>= 1) v += __shfl_xor(v, off, 64);
    return v;
}

// ---- 1: qf[b][h] = bq[h] + query[b,:] . Wq[h,:]  (block per h) ----
__global__ void qf_kernel(const float* __restrict__ query, const float* __restrict__ Wq,
                          const float* __restrict__ bq, float* __restrict__ qf) {
    int h = blockIdx.x;
    int tid = threadIdx.x;            // 256
    int wv = tid >> 6, lane = tid & 63;
    int k0 = tid * 4;
    f4 w = ld4(Wq + (size_t)h * HD + k0);
    __shared__ float red[4][NB];
    float acc[NB];
    #pragma unroll
    for (int b = 0; b < NB; ++b) {
        f4 q = ld4(query + b * HD + k0);
        acc[b] = w.x * q.x + w.y * q.y + w.z * q.z + w.w * q.w;
    }
    #pragma unroll
    for (int b = 0; b < NB; ++b) {
        float r = waveReduce(acc[b]);
        if (lane == 0) red[wv][b] = r;
    }
    __syncthreads();
    if (tid < NB) {
        float s = red[0][tid] + red[1][tid] + red[2][tid] + red[3][tid];
        qf[tid * HD + h] = s + bq[h];
    }
}

// ---- 2 (fused): per block = 16 rows of one batch.
//      Phase A: energies (4 rows/wave, 2-stage pipelined loads, nt), mask-skipped.
//      Phase B: raw-exp weighted states partial (compaction + 4-deep pipeline, nt). ----
__global__ __launch_bounds__(256) void fusedEC_kernel(
    const float* __restrict__ sf, const float* __restrict__ qf,
    const float* __restrict__ Wc, const float* __restrict__ vv,
    const float* __restrict__ coverage, const int* __restrict__ mask,
    const int* __restrict__ is_cov_p, const float* __restrict__ states,
    float* __restrict__ e_out, float* __restrict__ cpart)
{
    int chunk = blockIdx.x;                 // 0..127
    int b = blockIdx.y;                     // 0..15
    int tid = threadIdx.x;                  // 256
    int wv = tid >> 6, lane = tid & 63;
    int l4 = lane * 4;
    int base_row = b * LS + chunk * LPER;   // 16 rows
    int row0 = base_row + wv * 4;           // this wave's 4 rows

    __shared__ float e_loc[LPER];

    // --- phase A: energies ---
    int covflag = *is_cov_p;
    int4 mk = *reinterpret_cast<const int4*>(mask + row0);
    bool m0 = mk.x != 0, m1 = mk.y != 0, m2 = mk.z != 0, m3 = mk.w != 0;
    float cov0 = (covflag && m0) ? coverage[row0 + 0] : 0.f;
    float cov1 = (covflag && m1) ? coverage[row0 + 1] : 0.f;
    float cov2 = (covflag && m2) ? coverage[row0 + 2] : 0.f;
    float cov3 = (covflag && m3) ? coverage[row0 + 3] : 0.f;

    const float* qfr = qf + b * HD + l4;
    const float* ps = sf + (size_t)row0 * HD + l4;
    float a0 = 0.f, a1 = 0.f, a2 = 0.f, a3 = 0.f;

    // 2-stage software pipeline on the k (h) dimension
    f4 sA0, sA1, sA2, sA3;
    if (m0) sA0 = ldnt4(ps);
    if (m1) sA1 = ldnt4(ps + HD);
    if (m2) sA2 = ldnt4(ps + 2 * HD);
    if (m3) sA3 = ldnt4(ps + 3 * HD);
    #pragma unroll
    for (int it = 0; it < 4; ++it) {
        int o = it * 256;
        f4 q  = ld4(qfr + o);
        f4 wc = ld4(Wc + o + l4);
        f4 vf = ld4(vv + o + l4);
        f4 sB0, sB1, sB2, sB3;
        if (it < 3) {
            int on = o + 256;
            if (m0) sB0 = ldnt4(ps + on);
            if (m1) sB1 = ldnt4(ps + HD + on);
            if (m2) sB2 = ldnt4(ps + 2 * HD + on);
            if (m3) sB3 = ldnt4(ps + 3 * HD + on);
        }
        if (m0) a0 += dotTanh(sA0, q, wc, vf, cov0);
        if (m1) a1 += dotTanh(sA1, q, wc, vf, cov1);
        if (m2) a2 += dotTanh(sA2, q, wc, vf, cov2);
        if (m3) a3 += dotTanh(sA3, q, wc, vf, cov3);
        if (it < 3) { sA0 = sB0; sA1 = sB1; sA2 = sB2; sA3 = sB3; }
    }

    // interleaved cross-lane reductions (4 independent chains pipeline)
    #pragma unroll
    for (int off = 32; off; off >>= 1) {
        a0 += __shfl_xor(a0, off, 64);
        a1 += __shfl_xor(a1, off, 64);
        a2 += __shfl_xor(a2, off, 64);
        a3 += __shfl_xor(a3, off, 64);
    }
    if (lane == 0) {
        f4 o;
        o.x = m0 ? a0 : -1e30f;
        o.y = m1 ? a1 : -1e30f;
        o.z = m2 ? a2 : -1e30f;
        o.w = m3 ? a3 : -1e30f;
        *reinterpret_cast<f4*>(e_out + row0) = o;
        e_loc[wv * 4 + 0] = o.x;
        e_loc[wv * 4 + 1] = o.y;
        e_loc[wv * 4 + 2] = o.z;
        e_loc[wv * 4 + 3] = o.w;
    }
    __syncthreads();

    // --- phase B: compacted raw-exp weighted states accumulation ---
    __shared__ float wq[LPER];
    __shared__ int ridx[LPER];
    __shared__ int snnz;
    if (tid < 64) {                   // wave 0 compacts nonzero rows
        float ev = (tid < LPER) ? e_loc[tid] : -1e30f;
        float w = __expf(ev);         // masked -> exp(-1e30) = 0
        unsigned long long bm = __ballot(w != 0.f);
        if (w != 0.f) {
            int pos = __popcll(bm & ((1ull << tid) - 1));
            wq[pos] = w;
            ridx[pos] = tid;
        }
        if (tid == 0) snnz = __popcll(bm);
    }
    __syncthreads();
    int nnz = snnz;
    int h0 = tid * 4;
    const float* sbase = states + (size_t)base_row * HD + h0;
    float ax = 0.f, ay = 0.f, az = 0.f, aw = 0.f;
    for (int i = 0; i < nnz; i += 4) {
        int j1 = i + 1, j2 = i + 2, j3 = i + 3;
        float w0 = wq[i];
        int   r0 = ridx[i];
        float w1 = (j1 < nnz) ? wq[j1] : 0.f;
        int   r1 = (j1 < nnz) ? ridx[j1] : r0;
        float w2 = (j2 < nnz) ? wq[j2] : 0.f;
        int   r2 = (j2 < nnz) ? ridx[j2] : r0;
        float w3 = (j3 < nnz) ? wq[j3] : 0.f;
        int   r3 = (j3 < nnz) ? ridx[j3] : r0;
        f4 s0 = ldnt4(sbase + ((size_t)r0 << 10));
        f4 s1 = ldnt4(sbase + ((size_t)r1 << 10));
        f4 s2 = ldnt4(sbase + ((size_t)r2 << 10));
        f4 s3 = ldnt4(sbase + ((size_t)r3 << 10));
        ax = fmaf(w0, s0.x, ax); ay = fmaf(w0, s0.y, ay); az = fmaf(w0, s0.z, az); aw = fmaf(w0, s0.w, aw);
        ax = fmaf(w1, s1.x, ax); ay = fmaf(w1, s1.y, ay); az = fmaf(w1, s1.z, az); aw = fmaf(w1, s1.w, aw);
        ax = fmaf(w2, s2.x, ax); ay = fmaf(w2, s2.y, ay); az = fmaf(w2, s2.z, az); aw = fmaf(w2, s2.w, aw);
        ax = fmaf(w3, s3.x, ax); ay = fmaf(w3, s3.y, ay); az = fmaf(w3, s3.z, az); aw = fmaf(w3, s3.w, aw);
    }
    f4 o; o.x = ax; o.y = ay; o.z = az; o.w = aw;
    *reinterpret_cast<f4*>(cpart + ((size_t)(b * NCH + chunk)) * HD + h0) = o;  // unnormalized
}

// ---- 3 (merged): blocks 0..15 = per-batch softmax finalize; blocks 16..79 = cpart reduce ----
__global__ __launch_bounds__(1024) void mid_kernel(
    const float* __restrict__ e, const float* __restrict__ coverage,
    const float* __restrict__ cpart, float* __restrict__ scale,
    float* __restrict__ csum, float* __restrict__ out_align, float* __restrict__ out_newcov)
{
    __shared__ float redm[16], reds[16];
    __shared__ float red4[4][256];
    if (blockIdx.x < 16) {
        int b = blockIdx.x;
        int t = threadIdx.x;              // 1024
        int wv = t >> 6, lane = t & 63;
        float v0 = e[b * LS + t];
        float v1 = e[b * LS + t + 1024];
        float mx = fmaxf(v0, v1);
        #pragma unroll
        for (int off = 32; off; off >>= 1) mx = fmaxf(mx, __shfl_xor(mx, off, 64));
        if (lane == 0) redm[wv] = mx;
        __syncthreads();
        mx = redm[0];
        #pragma unroll
        for (int i = 1; i < 16; ++i) mx = fmaxf(mx, redm[i]);
        float e0 = __expf(v0 - mx), e1 = __expf(v1 - mx);
        float s = e0 + e1;
        #pragma unroll
        for (int off = 32; off; off >>= 1) s += __shfl_xor(s, off, 64);
        if (lane == 0) reds[wv] = s;
        __syncthreads();
        s = 0.f;
        #pragma unroll
        for (int i = 0; i < 16; ++i) s += reds[i];
        float invZ = 1.f / s;
        if (t == 0) scale[b] = __expf(-mx) * invZ;   // = 1 / sum(exp(e))
        int i0 = b * LS + t, i1 = i0 + 1024;
        float p0 = e0 * invZ, p1 = e1 * invZ;
        out_align[i0] = p0;
        out_align[i1] = p1;
        out_newcov[i0] = coverage[i0] + p0;
        out_newcov[i1] = coverage[i1] + p1;
    } else {
        int blk = blockIdx.x - 16;        // 0..63
        int tt = threadIdx.x & 255;
        int g = threadIdx.x >> 8;         // 0..3: each group sums 32 chunks
        int elem = blk * 256 + tt;        // 0..16383 = (b,h)
        int b = elem >> 10, h = elem & 1023;
        const float* p = cpart + (((size_t)(b * NCH + g * 32)) << 10) + h;
        float s = 0.f;
        #pragma unroll
        for (int ch = 0; ch < 32; ++ch) s += p[(size_t)ch << 10];
        red4[g][tt] = s;
        __syncthreads();
        if (g == 0) csum[elem] = red4[0][tt] + red4[1][tt] + red4[2][tt] + red4[3][tt];
    }
}

// ---- 4: attn_h[b][h] = bout[h] + scale[b]*<Wout_c, csum[b]> + <Wout_q, query[b]> ----
__global__ void out_kernel(const float* __restrict__ csum, const float* __restrict__ query,
                           const float* __restrict__ Wout, const float* __restrict__ bout,
                           const float* __restrict__ scale, float* __restrict__ attn) {
    int h = blockIdx.x;
    int tid = threadIdx.x;            // 256
    int wv = tid >> 6, lane = tid & 63;
    int j0 = tid * 8;
    const float* wr = Wout + (size_t)h * (2 * HD);
    f4 w0 = ld4(wr + j0);
    f4 w1 = ld4(wr + j0 + 4);
    const float* src = (j0 < HD) ? (csum + j0) : (query + j0 - HD);   // waves 0,1: csum; 2,3: query
    __shared__ float red[4][NB];
    float acc[NB];
    #pragma unroll
    for (int b = 0; b < NB; ++b) {
        f4 x0 = ld4(src + b * HD);
        f4 x1 = ld4(src + b * HD + 4);
        acc[b] = w0.x * x0.x + w0.y * x0.y + w0.z * x0.z + w0.w * x0.w
               + w1.x * x1.x + w1.y * x1.y + w1.z * x1.z + w1.w * x1.w;
    }
    #pragma unroll
    for (int b = 0; b < NB; ++b) {
        float r = waveReduce(acc[b]);
        if (lane == 0) red[wv][b] = r;
    }
    __syncthreads();
    if (tid < NB) {
        float cpartial = red[0][tid] + red[1][tid];   // csum part
        float qpartial = red[2][tid] + red[3][tid];   // query part
        attn[tid * HD + h] = cpartial * scale[tid] + qpartial + bout[h];
    }
}

extern "C" void kernel_launch(void* const* d_in, const int* in_sizes, int n_in,
                              void* d_out, int out_size, void* d_ws, size_t ws_size,
                              hipStream_t stream) {
    const float* query    = (const float*)d_in[0];
    const float* states   = (const float*)d_in[1];
    const float* sf       = (const float*)d_in[2];
    const float* coverage = (const float*)d_in[3];
    const int*   mask     = (const int*)d_in[4];
    const int*   is_cov   = (const int*)d_in[5];
    const float* Wq       = (const float*)d_in[6];
    const float* bq       = (const float*)d_in[7];
    const float* Wc       = (const float*)d_in[8];
    const float* v        = (const float*)d_in[9];
    const float* Wout     = (const float*)d_in[10];
    const float* bout     = (const float*)d_in[11];

    float* out      = (float*)d_out;
    float* attn     = out;                 // (16,1,1024)  = 16384
    float* newcov   = out + 16384;         // (16,2048,1)  = 32768
    float* alignout = out + 49152;         // (16,2048,1)  = 32768

    float* w  = (float*)d_ws;
    float* qf      = w;                          // 16*1024     = 16384
    float* e       = w + 16384;                  // 16*2048     = 32768
    float* cpart   = w + 49152;                  // 16*128*1024 = 2097152
    float* scale   = w + 49152 + 2097152;        // 16
    float* csum    = scale + 16;                 // 16*1024

    // 1: query features (reads Wq once, 4 MB, L3-resident across replays)
    qf_kernel<<<dim3(HD), dim3(256), 0, stream>>>(query, Wq, bq, qf);
    // 2: fused energies + raw-exp weighted partial contexts (~128 MB masked nt streams)
    fusedEC_kernel<<<dim3(NCH, NB), dim3(256), 0, stream>>>(
        sf, qf, Wc, v, coverage, mask, is_cov, states, e, cpart);
    // 3: softmax finalize (align/newcov/scale) + cpart reduce, role-split
    mid_kernel<<<dim3(80), dim3(1024), 0, stream>>>(e, coverage, cpart, scale, csum, alignout, newcov);
    // 4: output projection (reads Wout once, 8 MB)
    out_kernel<<<dim3(HD), dim3(256), 0, stream>>>(csum, query, Wout, bout, scale, attn);
}

// Round 8
// 56.870 us; speedup vs baseline: 1.1398x; 1.1398x over previous
//
#include <hip/hip_runtime.h>
#include <cfloat>

#define HD 1024
#define LS 2048
#define NB 16
#define LCHUNK 64            // chunks per batch (32 rows each)
#define LPER   (LS / LCHUNK) // 32 rows per chunk

struct f4 { float x, y, z, w; };

__device__ inline f4 ld4(const float* p) { return *reinterpret_cast<const f4*>(p); }

__device__ inline float ftanh(float x) {
    x = fminf(10.f, fmaxf(-10.f, x));
    float t = __expf(2.f * x);
    return 1.f - 2.f * __builtin_amdgcn_rcpf(t + 1.f);
}

__device__ inline float dotTanh(const f4& s, const f4& q, const f4& wc, const f4& v, float covs) {
    return ftanh(s.x + q.x + covs * wc.x) * v.x
         + ftanh(s.y + q.y + covs * wc.y) * v.y
         + ftanh(s.z + q.z + covs * wc.z) * v.z
         + ftanh(s.w + q.w + covs * wc.w) * v.w;
}

__device__ inline float waveReduce(float v) {
    #pragma unroll
    for (int off = 32; off; off >>= 1) v += __shfl_xor(v, off, 64);
    return v;
}

// ---- 1: qf[b][h] = bq[h] + query[b,:] . Wq[h,:]  (block per h) ----
__global__ void qf_kernel(const float* __restrict__ query, const float* __restrict__ Wq,
                          const float* __restrict__ bq, float* __restrict__ qf) {
    int h = blockIdx.x;
    int tid = threadIdx.x;            // 256
    int wv = tid >> 6, lane = tid & 63;
    int k0 = tid * 4;
    f4 w = ld4(Wq + (size_t)h * HD + k0);
    __shared__ float red[4][NB];
    float acc[NB];
    #pragma unroll
    for (int b = 0; b < NB; ++b) {
        f4 q = ld4(query + b * HD + k0);
        acc[b] = w.x * q.x + w.y * q.y + w.z * q.z + w.w * q.w;
    }
    #pragma unroll
    for (int b = 0; b < NB; ++b) {
        float r = waveReduce(acc[b]);
        if (lane == 0) red[wv][b] = r;
    }
    __syncthreads();
    if (tid < NB) {
        float s = red[0][tid] + red[1][tid] + red[2][tid] + red[3][tid];
        qf[tid * HD + h] = s + bq[h];
    }
}

// ---- 2 (fused): per block = 32 rows of one batch.
//      Phase A: energies (8 rows/wave, depth-2 pipelined loads), mask-skipped.
//      Phase B: raw-exp weighted states partial (compaction + 4-deep pipeline). ----
__global__ __launch_bounds__(256) void fusedEC_kernel(
    const float* __restrict__ sf, const float* __restrict__ qf,
    const float* __restrict__ Wc, const float* __restrict__ vv,
    const float* __restrict__ coverage, const int* __restrict__ mask,
    const int* __restrict__ is_cov_p, const float* __restrict__ states,
    float* __restrict__ e_out, float* __restrict__ cpart)
{
    int chunk = blockIdx.x;                 // 0..63
    int b = blockIdx.y;                     // 0..15
    int tid = threadIdx.x;                  // 256
    int wv = tid >> 6, lane = tid & 63;
    int l4 = lane * 4;
    int base_row = b * LS + chunk * LPER;   // 32 rows
    int row0 = base_row + wv * 8;           // this wave's 8 rows

    __shared__ float e_loc[LPER];

    // --- phase A: energies ---
    int covflag = *is_cov_p;
    int4 mk0 = *reinterpret_cast<const int4*>(mask + row0);
    int4 mk1 = *reinterpret_cast<const int4*>(mask + row0 + 4);
    bool m[8] = { mk0.x != 0, mk0.y != 0, mk0.z != 0, mk0.w != 0,
                  mk1.x != 0, mk1.y != 0, mk1.z != 0, mk1.w != 0 };
    float cov[8];
    #pragma unroll
    for (int r = 0; r < 8; ++r) cov[r] = (covflag && m[r]) ? coverage[row0 + r] : 0.f;

    const float* qfr = qf + b * HD + l4;
    const float* ps = sf + (size_t)row0 * HD + l4;
    float acc[8] = {0.f, 0.f, 0.f, 0.f, 0.f, 0.f, 0.f, 0.f};

    // depth-2 software pipeline on the k (h) dimension: 16 loads in flight
    f4 sA[8];
    #pragma unroll
    for (int r = 0; r < 8; ++r) if (m[r]) sA[r] = ld4(ps + (size_t)r * HD);
    #pragma unroll
    for (int it = 0; it < 4; ++it) {
        int o = it * 256;
        f4 q  = ld4(qfr + o);
        f4 wc = ld4(Wc + o + l4);
        f4 vf = ld4(vv + o + l4);
        f4 sB[8];
        if (it < 3) {
            #pragma unroll
            for (int r = 0; r < 8; ++r) if (m[r]) sB[r] = ld4(ps + (size_t)r * HD + o + 256);
        }
        #pragma unroll
        for (int r = 0; r < 8; ++r) if (m[r]) acc[r] += dotTanh(sA[r], q, wc, vf, cov[r]);
        if (it < 3) {
            #pragma unroll
            for (int r = 0; r < 8; ++r) sA[r] = sB[r];
        }
    }

    // interleaved cross-lane reductions (8 independent chains pipeline)
    #pragma unroll
    for (int off = 32; off; off >>= 1) {
        #pragma unroll
        for (int r = 0; r < 8; ++r) acc[r] += __shfl_xor(acc[r], off, 64);
    }
    if (lane == 0) {
        float ev[8];
        #pragma unroll
        for (int r = 0; r < 8; ++r) ev[r] = m[r] ? acc[r] : -1e30f;
        f4 o0, o1;
        o0.x = ev[0]; o0.y = ev[1]; o0.z = ev[2]; o0.w = ev[3];
        o1.x = ev[4]; o1.y = ev[5]; o1.z = ev[6]; o1.w = ev[7];
        *reinterpret_cast<f4*>(e_out + row0) = o0;
        *reinterpret_cast<f4*>(e_out + row0 + 4) = o1;
        #pragma unroll
        for (int r = 0; r < 8; ++r) e_loc[wv * 8 + r] = ev[r];
    }
    __syncthreads();

    // --- phase B: compacted raw-exp weighted states accumulation ---
    __shared__ float wq[LPER];
    __shared__ int ridx[LPER];
    __shared__ int snnz;
    if (tid < 64) {                   // wave 0 compacts nonzero rows
        float ev = (tid < LPER) ? e_loc[tid] : -1e30f;
        float w = __expf(ev);         // masked -> exp(-1e30) = 0
        unsigned long long bm = __ballot(w != 0.f);
        if (w != 0.f) {
            int pos = __popcll(bm & ((1ull << tid) - 1));
            wq[pos] = w;
            ridx[pos] = tid;
        }
        if (tid == 0) snnz = __popcll(bm);
    }
    __syncthreads();
    int nnz = snnz;
    int h0 = tid * 4;
    const float* sbase = states + (size_t)base_row * HD + h0;
    float ax = 0.f, ay = 0.f, az = 0.f, aw = 0.f;
    for (int i = 0; i < nnz; i += 4) {
        int j1 = i + 1, j2 = i + 2, j3 = i + 3;
        float w0 = wq[i];
        int   r0 = ridx[i];
        float w1 = (j1 < nnz) ? wq[j1] : 0.f;
        int   r1 = (j1 < nnz) ? ridx[j1] : r0;
        float w2 = (j2 < nnz) ? wq[j2] : 0.f;
        int   r2 = (j2 < nnz) ? ridx[j2] : r0;
        float w3 = (j3 < nnz) ? wq[j3] : 0.f;
        int   r3 = (j3 < nnz) ? ridx[j3] : r0;
        f4 s0 = ld4(sbase + ((size_t)r0 << 10));
        f4 s1 = ld4(sbase + ((size_t)r1 << 10));
        f4 s2 = ld4(sbase + ((size_t)r2 << 10));
        f4 s3 = ld4(sbase + ((size_t)r3 << 10));
        ax = fmaf(w0, s0.x, ax); ay = fmaf(w0, s0.y, ay); az = fmaf(w0, s0.z, az); aw = fmaf(w0, s0.w, aw);
        ax = fmaf(w1, s1.x, ax); ay = fmaf(w1, s1.y, ay); az = fmaf(w1, s1.z, az); aw = fmaf(w1, s1.w, aw);
        ax = fmaf(w2, s2.x, ax); ay = fmaf(w2, s2.y, ay); az = fmaf(w2, s2.z, az); aw = fmaf(w2, s2.w, aw);
        ax = fmaf(w3, s3.x, ax); ay = fmaf(w3, s3.y, ay); az = fmaf(w3, s3.z, az); aw = fmaf(w3, s3.w, aw);
    }
    f4 o; o.x = ax; o.y = ay; o.z = az; o.w = aw;
    *reinterpret_cast<f4*>(cpart + ((size_t)(b * LCHUNK + chunk)) * HD + h0) = o;  // unnormalized
}

// ---- 3 (merged): blocks 0..15 = per-batch softmax finalize; blocks 16..79 = cpart reduce ----
__global__ __launch_bounds__(1024) void mid_kernel(
    const float* __restrict__ e, const float* __restrict__ coverage,
    const float* __restrict__ cpart, float* __restrict__ scale,
    float* __restrict__ csum, float* __restrict__ out_align, float* __restrict__ out_newcov)
{
    __shared__ float redm[16], reds[16];
    __shared__ float red4[4][256];
    if (blockIdx.x < 16) {
        int b = blockIdx.x;
        int t = threadIdx.x;              // 1024
        int wv = t >> 6, lane = t & 63;
        float v0 = e[b * LS + t];
        float v1 = e[b * LS + t + 1024];
        float mx = fmaxf(v0, v1);
        #pragma unroll
        for (int off = 32; off; off >>= 1) mx = fmaxf(mx, __shfl_xor(mx, off, 64));
        if (lane == 0) redm[wv] = mx;
        __syncthreads();
        mx = redm[0];
        #pragma unroll
        for (int i = 1; i < 16; ++i) mx = fmaxf(mx, redm[i]);
        float e0 = __expf(v0 - mx), e1 = __expf(v1 - mx);
        float s = e0 + e1;
        #pragma unroll
        for (int off = 32; off; off >>= 1) s += __shfl_xor(s, off, 64);
        if (lane == 0) reds[wv] = s;
        __syncthreads();
        s = 0.f;
        #pragma unroll
        for (int i = 0; i < 16; ++i) s += reds[i];
        float invZ = 1.f / s;
        if (t == 0) scale[b] = __expf(-mx) * invZ;   // = 1 / sum(exp(e))
        int i0 = b * LS + t, i1 = i0 + 1024;
        float p0 = e0 * invZ, p1 = e1 * invZ;
        out_align[i0] = p0;
        out_align[i1] = p1;
        out_newcov[i0] = coverage[i0] + p0;
        out_newcov[i1] = coverage[i1] + p1;
    } else {
        int blk = blockIdx.x - 16;        // 0..63
        int tt = threadIdx.x & 255;
        int g = threadIdx.x >> 8;         // 0..3: each group sums 16 chunks
        int elem = blk * 256 + tt;        // 0..16383 = (b,h)
        int b = elem >> 10, h = elem & 1023;
        const float* p = cpart + (((size_t)(b * LCHUNK + g * 16)) << 10) + h;
        float s = 0.f;
        #pragma unroll
        for (int ch = 0; ch < 16; ++ch) s += p[(size_t)ch << 10];
        red4[g][tt] = s;
        __syncthreads();
        if (g == 0) csum[elem] = red4[0][tt] + red4[1][tt] + red4[2][tt] + red4[3][tt];
    }
}

// ---- 4: attn_h[b][h] = bout[h] + scale[b]*<Wout_c, csum[b]> + <Wout_q, query[b]> ----
__global__ void out_kernel(const float* __restrict__ csum, const float* __restrict__ query,
                           const float* __restrict__ Wout, const float* __restrict__ bout,
                           const float* __restrict__ scale, float* __restrict__ attn) {
    int h = blockIdx.x;
    int tid = threadIdx.x;            // 256
    int wv = tid >> 6, lane = tid & 63;
    int j0 = tid * 8;
    const float* wr = Wout + (size_t)h * (2 * HD);
    f4 w0 = ld4(wr + j0);
    f4 w1 = ld4(wr + j0 + 4);
    const float* src = (j0 < HD) ? (csum + j0) : (query + j0 - HD);   // waves 0,1: csum; 2,3: query
    __shared__ float red[4][NB];
    float acc[NB];
    #pragma unroll
    for (int b = 0; b < NB; ++b) {
        f4 x0 = ld4(src + b * HD);
        f4 x1 = ld4(src + b * HD + 4);
        acc[b] = w0.x * x0.x + w0.y * x0.y + w0.z * x0.z + w0.w * x0.w
               + w1.x * x1.x + w1.y * x1.y + w1.z * x1.z + w1.w * x1.w;
    }
    #pragma unroll
    for (int b = 0; b < NB; ++b) {
        float r = waveReduce(acc[b]);
        if (lane == 0) red[wv][b] = r;
    }
    __syncthreads();
    if (tid < NB) {
        float cpartial = red[0][tid] + red[1][tid];   // csum part
        float qpartial = red[2][tid] + red[3][tid];   // query part
        attn[tid * HD + h] = cpartial * scale[tid] + qpartial + bout[h];
    }
}

extern "C" void kernel_launch(void* const* d_in, const int* in_sizes, int n_in,
                              void* d_out, int out_size, void* d_ws, size_t ws_size,
                              hipStream_t stream) {
    const float* query    = (const float*)d_in[0];
    const float* states   = (const float*)d_in[1];
    const float* sf       = (const float*)d_in[2];
    const float* coverage = (const float*)d_in[3];
    const int*   mask     = (const int*)d_in[4];
    const int*   is_cov   = (const int*)d_in[5];
    const float* Wq       = (const float*)d_in[6];
    const float* bq       = (const float*)d_in[7];
    const float* Wc       = (const float*)d_in[8];
    const float* v        = (const float*)d_in[9];
    const float* Wout     = (const float*)d_in[10];
    const float* bout     = (const float*)d_in[11];

    float* out      = (float*)d_out;
    float* attn     = out;                 // (16,1,1024)  = 16384
    float* newcov   = out + 16384;         // (16,2048,1)  = 32768
    float* alignout = out + 49152;         // (16,2048,1)  = 32768

    float* w  = (float*)d_ws;
    float* qf      = w;                          // 16*1024    = 16384
    float* e       = w + 16384;                  // 16*2048    = 32768
    float* cpart   = w + 49152;                  // 16*64*1024 = 1048576
    float* scale   = w + 49152 + 1048576;        // 16
    float* csum    = scale + 16;                 // 16*1024

    // 1: query features (reads Wq once, 4 MB)
    qf_kernel<<<dim3(HD), dim3(256), 0, stream>>>(query, Wq, bq, qf);
    // 2: fused energies + raw-exp weighted partial contexts (~128 MB masked streams)
    fusedEC_kernel<<<dim3(LCHUNK, NB), dim3(256), 0, stream>>>(
        sf, qf, Wc, v, coverage, mask, is_cov, states, e, cpart);
    // 3: softmax finalize (align/newcov/scale) + cpart reduce, role-split
    mid_kernel<<<dim3(80), dim3(1024), 0, stream>>>(e, coverage, cpart, scale, csum, alignout, newcov);
    // 4: output projection (reads Wout once, 8 MB)
    out_kernel<<<dim3(HD), dim3(256), 0, stream>>>(csum, query, Wout, bout, scale, attn);
}

// Round 9
// 56.796 us; speedup vs baseline: 1.1413x; 1.0013x over previous
//
#include <hip/hip_runtime.h>
#include <cfloat>

#define HD 1024
#define LS 2048
#define NB 16
#define NCH 128              // chunks per batch (16 rows each)
#define LPER (LS / NCH)      // 16 rows per chunk

struct f4 { float x, y, z, w; };

__device__ inline f4 ld4(const float* p) { return *reinterpret_cast<const f4*>(p); }

__device__ inline float ftanh(float x) {
    x = fminf(10.f, fmaxf(-10.f, x));
    float t = __expf(2.f * x);
    return 1.f - 2.f * __builtin_amdgcn_rcpf(t + 1.f);
}

__device__ inline float dotTanh(const f4& s, const f4& q, const f4& wc, const f4& v, float covs) {
    return ftanh(s.x + q.x + covs * wc.x) * v.x
         + ftanh(s.y + q.y + covs * wc.y) * v.y
         + ftanh(s.z + q.z + covs * wc.z) * v.z
         + ftanh(s.w + q.w + covs * wc.w) * v.w;
}

__device__ inline float waveReduce(float v) {
    #pragma unroll
    for (int off = 32; off; off >>= 1) v += __shfl_xor(v, off, 64);
    return v;
}

// ---- 1: qf[b][h] = bq[h] + query[b,:] . Wq[h,:]  (block per h) ----
__global__ void qf_kernel(const float* __restrict__ query, const float* __restrict__ Wq,
                          const float* __restrict__ bq, float* __restrict__ qf) {
    int h = blockIdx.x;
    int tid = threadIdx.x;            // 256
    int wv = tid >> 6, lane = tid & 63;
    int k0 = tid * 4;
    f4 w = ld4(Wq + (size_t)h * HD + k0);
    __shared__ float red[4][NB];
    float acc[NB];
    #pragma unroll
    for (int b = 0; b < NB; ++b) {
        f4 q = ld4(query + b * HD + k0);
        acc[b] = w.x * q.x + w.y * q.y + w.z * q.z + w.w * q.w;
    }
    #pragma unroll
    for (int b = 0; b < NB; ++b) {
        float r = waveReduce(acc[b]);
        if (lane == 0) red[wv][b] = r;
    }
    __syncthreads();
    if (tid < NB) {
        float s = red[0][tid] + red[1][tid] + red[2][tid] + red[3][tid];
        qf[tid * HD + h] = s + bq[h];
    }
}

// ---- 2 (fused): per block = 16 rows of one batch. 2048 blocks -> 8 blocks/CU.
//      Phase A: energies (4 rows/wave), mask-skipped.
//      Phase B: raw-exp weighted states partial (compaction + 4-deep pipeline). ----
__global__ __launch_bounds__(256) void fusedEC_kernel(
    const float* __restrict__ sf, const float* __restrict__ qf,
    const float* __restrict__ Wc, const float* __restrict__ vv,
    const float* __restrict__ coverage, const int* __restrict__ mask,
    const int* __restrict__ is_cov_p, const float* __restrict__ states,
    float* __restrict__ e_out, float* __restrict__ cpart)
{
    int chunk = blockIdx.x;                 // 0..127
    int b = blockIdx.y;                     // 0..15
    int tid = threadIdx.x;                  // 256
    int wv = tid >> 6, lane = tid & 63;
    int l4 = lane * 4;
    int base_row = b * LS + chunk * LPER;   // 16 rows
    int row0 = base_row + wv * 4;           // this wave's 4 rows

    __shared__ float e_loc[LPER];

    // --- phase A: energies ---
    int covflag = *is_cov_p;
    int4 mk = *reinterpret_cast<const int4*>(mask + row0);
    bool m0 = mk.x != 0, m1 = mk.y != 0, m2 = mk.z != 0, m3 = mk.w != 0;
    float cov0 = (covflag && m0) ? coverage[row0 + 0] : 0.f;
    float cov1 = (covflag && m1) ? coverage[row0 + 1] : 0.f;
    float cov2 = (covflag && m2) ? coverage[row0 + 2] : 0.f;
    float cov3 = (covflag && m3) ? coverage[row0 + 3] : 0.f;

    const float* qfr = qf + b * HD + l4;
    const float* ps = sf + (size_t)row0 * HD + l4;
    float a0 = 0.f, a1 = 0.f, a2 = 0.f, a3 = 0.f;

    #pragma unroll
    for (int it = 0; it < 4; ++it) {
        int o = it * 256;
        f4 q  = ld4(qfr + o);
        f4 wc = ld4(Wc + o + l4);
        f4 vf = ld4(vv + o + l4);
        f4 s0, s1, s2, s3;
        if (m0) s0 = ld4(ps + o);
        if (m1) s1 = ld4(ps + HD + o);
        if (m2) s2 = ld4(ps + 2 * HD + o);
        if (m3) s3 = ld4(ps + 3 * HD + o);
        if (m0) a0 += dotTanh(s0, q, wc, vf, cov0);
        if (m1) a1 += dotTanh(s1, q, wc, vf, cov1);
        if (m2) a2 += dotTanh(s2, q, wc, vf, cov2);
        if (m3) a3 += dotTanh(s3, q, wc, vf, cov3);
    }

    // interleaved cross-lane reductions (4 independent chains pipeline)
    #pragma unroll
    for (int off = 32; off; off >>= 1) {
        a0 += __shfl_xor(a0, off, 64);
        a1 += __shfl_xor(a1, off, 64);
        a2 += __shfl_xor(a2, off, 64);
        a3 += __shfl_xor(a3, off, 64);
    }
    if (lane == 0) {
        f4 o;
        o.x = m0 ? a0 : -1e30f;
        o.y = m1 ? a1 : -1e30f;
        o.z = m2 ? a2 : -1e30f;
        o.w = m3 ? a3 : -1e30f;
        *reinterpret_cast<f4*>(e_out + row0) = o;
        e_loc[wv * 4 + 0] = o.x;
        e_loc[wv * 4 + 1] = o.y;
        e_loc[wv * 4 + 2] = o.z;
        e_loc[wv * 4 + 3] = o.w;
    }
    __syncthreads();

    // --- phase B: compacted raw-exp weighted states accumulation ---
    __shared__ float wq[LPER];
    __shared__ int ridx[LPER];
    __shared__ int snnz;
    if (tid < 64) {                   // wave 0 compacts nonzero rows
        float ev = (tid < LPER) ? e_loc[tid] : -1e30f;
        float w = __expf(ev);         // masked -> exp(-1e30) = 0
        unsigned long long bm = __ballot(w != 0.f);
        if (w != 0.f) {
            int pos = __popcll(bm & ((1ull << tid) - 1));
            wq[pos] = w;
            ridx[pos] = tid;
        }
        if (tid == 0) snnz = __popcll(bm);
    }
    __syncthreads();
    int nnz = snnz;
    int h0 = tid * 4;
    const float* sbase = states + (size_t)base_row * HD + h0;
    float ax = 0.f, ay = 0.f, az = 0.f, aw = 0.f;
    for (int i = 0; i < nnz; i += 4) {
        int j1 = i + 1, j2 = i + 2, j3 = i + 3;
        float w0 = wq[i];
        int   r0 = ridx[i];
        float w1 = (j1 < nnz) ? wq[j1] : 0.f;
        int   r1 = (j1 < nnz) ? ridx[j1] : r0;
        float w2 = (j2 < nnz) ? wq[j2] : 0.f;
        int   r2 = (j2 < nnz) ? ridx[j2] : r0;
        float w3 = (j3 < nnz) ? wq[j3] : 0.f;
        int   r3 = (j3 < nnz) ? ridx[j3] : r0;
        f4 s0 = ld4(sbase + ((size_t)r0 << 10));
        f4 s1 = ld4(sbase + ((size_t)r1 << 10));
        f4 s2 = ld4(sbase + ((size_t)r2 << 10));
        f4 s3 = ld4(sbase + ((size_t)r3 << 10));
        ax = fmaf(w0, s0.x, ax); ay = fmaf(w0, s0.y, ay); az = fmaf(w0, s0.z, az); aw = fmaf(w0, s0.w, aw);
        ax = fmaf(w1, s1.x, ax); ay = fmaf(w1, s1.y, ay); az = fmaf(w1, s1.z, az); aw = fmaf(w1, s1.w, aw);
        ax = fmaf(w2, s2.x, ax); ay = fmaf(w2, s2.y, ay); az = fmaf(w2, s2.z, az); aw = fmaf(w2, s2.w, aw);
        ax = fmaf(w3, s3.x, ax); ay = fmaf(w3, s3.y, ay); az = fmaf(w3, s3.z, az); aw = fmaf(w3, s3.w, aw);
    }
    f4 o; o.x = ax; o.y = ay; o.z = az; o.w = aw;
    *reinterpret_cast<f4*>(cpart + ((size_t)(b * NCH + chunk)) * HD + h0) = o;  // unnormalized
}

// ---- 3 (merged): blocks 0..15 = per-batch softmax finalize; blocks 16..79 = cpart reduce ----
__global__ __launch_bounds__(1024) void mid_kernel(
    const float* __restrict__ e, const float* __restrict__ coverage,
    const float* __restrict__ cpart, float* __restrict__ scale,
    float* __restrict__ csum, float* __restrict__ out_align, float* __restrict__ out_newcov)
{
    __shared__ float redm[16], reds[16];
    __shared__ float red4[4][256];
    if (blockIdx.x < 16) {
        int b = blockIdx.x;
        int t = threadIdx.x;              // 1024
        int wv = t >> 6, lane = t & 63;
        float v0 = e[b * LS + t];
        float v1 = e[b * LS + t + 1024];
        float mx = fmaxf(v0, v1);
        #pragma unroll
        for (int off = 32; off; off >>= 1) mx = fmaxf(mx, __shfl_xor(mx, off, 64));
        if (lane == 0) redm[wv] = mx;
        __syncthreads();
        mx = redm[0];
        #pragma unroll
        for (int i = 1; i < 16; ++i) mx = fmaxf(mx, redm[i]);
        float e0 = __expf(v0 - mx), e1 = __expf(v1 - mx);
        float s = e0 + e1;
        #pragma unroll
        for (int off = 32; off; off >>= 1) s += __shfl_xor(s, off, 64);
        if (lane == 0) reds[wv] = s;
        __syncthreads();
        s = 0.f;
        #pragma unroll
        for (int i = 0; i < 16; ++i) s += reds[i];
        float invZ = 1.f / s;
        if (t == 0) scale[b] = __expf(-mx) * invZ;   // = 1 / sum(exp(e))
        int i0 = b * LS + t, i1 = i0 + 1024;
        float p0 = e0 * invZ, p1 = e1 * invZ;
        out_align[i0] = p0;
        out_align[i1] = p1;
        out_newcov[i0] = coverage[i0] + p0;
        out_newcov[i1] = coverage[i1] + p1;
    } else {
        int blk = blockIdx.x - 16;        // 0..63
        int tt = threadIdx.x & 255;
        int g = threadIdx.x >> 8;         // 0..3: each group sums 32 chunks
        int elem = blk * 256 + tt;        // 0..16383 = (b,h)
        int b = elem >> 10, h = elem & 1023;
        const float* p = cpart + (((size_t)(b * NCH + g * 32)) << 10) + h;
        float s = 0.f;
        #pragma unroll
        for (int ch = 0; ch < 32; ++ch) s += p[(size_t)ch << 10];
        red4[g][tt] = s;
        __syncthreads();
        if (g == 0) csum[elem] = red4[0][tt] + red4[1][tt] + red4[2][tt] + red4[3][tt];
    }
}

// ---- 4: attn_h[b][h] = bout[h] + scale[b]*<Wout_c, csum[b]> + <Wout_q, query[b]> ----
__global__ void out_kernel(const float* __restrict__ csum, const float* __restrict__ query,
                           const float* __restrict__ Wout, const float* __restrict__ bout,
                           const float* __restrict__ scale, float* __restrict__ attn) {
    int h = blockIdx.x;
    int tid = threadIdx.x;            // 256
    int wv = tid >> 6, lane = tid & 63;
    int j0 = tid * 8;
    const float* wr = Wout + (size_t)h * (2 * HD);
    f4 w0 = ld4(wr + j0);
    f4 w1 = ld4(wr + j0 + 4);
    const float* src = (j0 < HD) ? (csum + j0) : (query + j0 - HD);   // waves 0,1: csum; 2,3: query
    __shared__ float red[4][NB];
    float acc[NB];
    #pragma unroll
    for (int b = 0; b < NB; ++b) {
        f4 x0 = ld4(src + b * HD);
        f4 x1 = ld4(src + b * HD + 4);
        acc[b] = w0.x * x0.x + w0.y * x0.y + w0.z * x0.z + w0.w * x0.w
               + w1.x * x1.x + w1.y * x1.y + w1.z * x1.z + w1.w * x1.w;
    }
    #pragma unroll
    for (int b = 0; b < NB; ++b) {
        float r = waveReduce(acc[b]);
        if (lane == 0) red[wv][b] = r;
    }
    __syncthreads();
    if (tid < NB) {
        float cpartial = red[0][tid] + red[1][tid];   // csum part
        float qpartial = red[2][tid] + red[3][tid];   // query part
        attn[tid * HD + h] = cpartial * scale[tid] + qpartial + bout[h];
    }
}

extern "C" void kernel_launch(void* const* d_in, const int* in_sizes, int n_in,
                              void* d_out, int out_size, void* d_ws, size_t ws_size,
                              hipStream_t stream) {
    const float* query    = (const float*)d_in[0];
    const float* states   = (const float*)d_in[1];
    const float* sf       = (const float*)d_in[2];
    const float* coverage = (const float*)d_in[3];
    const int*   mask     = (const int*)d_in[4];
    const int*   is_cov   = (const int*)d_in[5];
    const float* Wq       = (const float*)d_in[6];
    const float* bq       = (const float*)d_in[7];
    const float* Wc       = (const float*)d_in[8];
    const float* v        = (const float*)d_in[9];
    const float* Wout     = (const float*)d_in[10];
    const float* bout     = (const float*)d_in[11];

    float* out      = (float*)d_out;
    float* attn     = out;                 // (16,1,1024)  = 16384
    float* newcov   = out + 16384;         // (16,2048,1)  = 32768
    float* alignout = out + 49152;         // (16,2048,1)  = 32768

    float* w  = (float*)d_ws;
    float* qf      = w;                          // 16*1024     = 16384
    float* e       = w + 16384;                  // 16*2048     = 32768
    float* cpart   = w + 49152;                  // 16*128*1024 = 2097152
    float* scale   = w + 49152 + 2097152;        // 16
    float* csum    = scale + 16;                 // 16*1024

    // 1: query features (reads Wq once, 4 MB)
    qf_kernel<<<dim3(HD), dim3(256), 0, stream>>>(query, Wq, bq, qf);
    // 2: fused energies + raw-exp weighted partial contexts (~128 MB masked streams)
    fusedEC_kernel<<<dim3(NCH, NB), dim3(256), 0, stream>>>(
        sf, qf, Wc, v, coverage, mask, is_cov, states, e, cpart);
    // 3: softmax finalize (align/newcov/scale) + cpart reduce, role-split
    mid_kernel<<<dim3(80), dim3(1024), 0, stream>>>(e, coverage, cpart, scale, csum, alignout, newcov);
    // 4: output projection (reads Wout once, 8 MB)
    out_kernel<<<dim3(HD), dim3(256), 0, stream>>>(csum, query, Wout, bout, scale, attn);
}